// Round 19
// baseline (480.691 us; speedup 1.0000x reference)
//
#include <hip/hip_runtime.h>

// LinearAttention, S=4096 B=8 D=1024.
// Algebraic form: K = elu(Wk x^T + bk)+1 (only nonlinear proj materialized);
//   MT[b][d][f] = sum_s K[s,d] x[s,f];  KVo = Wvo*MT^T + bvo (x) Ksum;
//   out = (elu(x Wq^T + bq)+1) @ KVo^T + bo.   Wvo = Wo Wv, bvo = Wo bv.
// gemm8p: 256^2, 8 phases/iter, 1 barrier/phase, vmcnt(6)@P3/P7.
// R19: kv_add eliminated — KVo computed as two accumulating GEMMs over the
// partial slabs (ACCUM epilogue flag); rank-1 term applied on the second pass.

typedef __bf16 bf16;
typedef __attribute__((ext_vector_type(8))) __bf16 bf16x8;
typedef __attribute__((ext_vector_type(4))) __bf16 bf16x4;
typedef __attribute__((ext_vector_type(4))) float f32x4;

static constexpr int S = 4096;
static constexpr int B = 8;
static constexpr int D = 1024;
static constexpr int SB = S * B;
static constexpr long long NELEM = (long long)SB * D;
static constexpr int TP = 66;   // transpose tile row stride (bank-conflict-tuned)

__device__ __forceinline__ void load_lds16(const bf16* g, void* l)
{
    __builtin_amdgcn_global_load_lds(
        (const __attribute__((address_space(1))) void*)g,
        (__attribute__((address_space(3))) void*)l, 16, 0, 0);
}

// ---------------- 3x weight fp32 -> bf16 convert (merged) ----------------
__global__ void cvt_w3(const float* __restrict__ w0, const float* __restrict__ w1,
                       const float* __restrict__ w2, bf16* __restrict__ o0,
                       bf16* __restrict__ o1, bf16* __restrict__ o2)
{
    const float* in;
    bf16* out;
    if (blockIdx.y == 0)      { in = w0; out = o0; }
    else if (blockIdx.y == 1) { in = w1; out = o1; }
    else                      { in = w2; out = o2; }
    int i = (blockIdx.x * blockDim.x + threadIdx.x) * 4;
    float4 v = *(const float4*)(in + i);
    bf16x4 o;
    o[0] = (bf16)v.x; o[1] = (bf16)v.y; o[2] = (bf16)v.z; o[3] = (bf16)v.w;
    *(bf16x4*)(out + i) = o;
}

// ---- x [S][B][D] fp32 -> xbp [B][S][D] bf16 AND xT [B][D][S] bf16 (one pass) ----
__global__ __launch_bounds__(256) void cvt_permute_both(
    const float* __restrict__ in, bf16* __restrict__ xbp, bf16* __restrict__ xT)
{
    __shared__ bf16 tile[64 * TP];   // tile[f][s], stride TP=66
    const int b  = blockIdx.z;
    const int s0 = blockIdx.x * 64;
    const int f0 = blockIdx.y * 64;
    const int t  = threadIdx.x;
    const int rl = t >> 3;           // 0..31
    const int c8 = (t & 7) * 8;      // 0..56
    const long long SD = (long long)S * D;

    #pragma unroll
    for (int p = 0; p < 2; ++p) {
        const int r = rl + p * 32;   // s offset in tile
        const float* src = in + (long long)(s0 + r) * (B * D) + b * D + f0 + c8;
        float4 v0 = *(const float4*)(src);
        float4 v1 = *(const float4*)(src + 4);
        bf16x8 o;
        o[0] = (bf16)v0.x; o[1] = (bf16)v0.y; o[2] = (bf16)v0.z; o[3] = (bf16)v0.w;
        o[4] = (bf16)v1.x; o[5] = (bf16)v1.y; o[6] = (bf16)v1.z; o[7] = (bf16)v1.w;
        *(bf16x8*)(xbp + b * SD + (long long)(s0 + r) * D + f0 + c8) = o;
        #pragma unroll
        for (int j = 0; j < 8; ++j)
            tile[(c8 + j) * TP + r] = o[j];
    }
    __syncthreads();
    #pragma unroll
    for (int p = 0; p < 2; ++p) {
        const int fr = rl + p * 32;  // f offset in tile
        *(bf16x8*)(xT + b * SD + (long long)(f0 + fr) * S + s0 + c8) =
            *(const bf16x8*)(&tile[fr * TP + c8]);
    }
}

// ---------------- Wv (fp32 [e][d]) -> WvT (bf16 [d][e]) ----------------
__global__ __launch_bounds__(256) void cvt_transpose_1024(
    const float* __restrict__ in, bf16* __restrict__ out)
{
    __shared__ bf16 tile[64 * TP];   // tile[d][e], stride TP
    const int e0 = blockIdx.y * 64;
    const int d0 = blockIdx.x * 64;
    const int t  = threadIdx.x;
    const int rl = t >> 3;
    const int c8 = (t & 7) * 8;
    #pragma unroll
    for (int p = 0; p < 2; ++p) {
        int r = rl + p * 32;
        float4 v0 = *(const float4*)(in + (long long)(e0 + r) * D + d0 + c8);
        float4 v1 = *(const float4*)(in + (long long)(e0 + r) * D + d0 + c8 + 4);
        bf16x8 o;
        o[0] = (bf16)v0.x; o[1] = (bf16)v0.y; o[2] = (bf16)v0.z; o[3] = (bf16)v0.w;
        o[4] = (bf16)v1.x; o[5] = (bf16)v1.y; o[6] = (bf16)v1.z; o[7] = (bf16)v1.w;
        #pragma unroll
        for (int j = 0; j < 8; ++j)
            tile[(c8 + j) * TP + r] = o[j];
    }
    __syncthreads();
    #pragma unroll
    for (int p = 0; p < 2; ++p) {
        int dr = rl + p * 32;
        *(bf16x8*)(out + (long long)(d0 + dr) * D + e0 + c8) =
            *(const bf16x8*)(&tile[dr * TP + c8]);
    }
}

// ---------------- bvo = Wo @ bv (fp32) ----------------
__global__ __launch_bounds__(256) void bvo_kernel(
    const float* __restrict__ Wo, const float* __restrict__ bv, float* __restrict__ bvo)
{
    const int row = blockIdx.x;
    const int t = threadIdx.x;
    float4 w = *(const float4*)(Wo + (long long)row * D + t * 4);
    float4 b = *(const float4*)(bv + t * 4);
    float s = w.x*b.x + w.y*b.y + w.z*b.z + w.w*b.w;
    __shared__ float red[256];
    red[t] = s; __syncthreads();
    for (int off = 128; off > 0; off >>= 1) {
        if (t < off) red[t] += red[t + off];
        __syncthreads();
    }
    if (t == 0) bvo[row] = red[0];
}

// ---------------- R3 ring GEMM (small shapes: Wvo prep only) ----------------
template<int BM, int BN, int WM, int WN, int EPI, int OUTF32, int BIASROW>
__global__ __launch_bounds__(WM * WN * 64, 2) void gemm_bt(
    const bf16* __restrict__ A, const bf16* __restrict__ Bm,
    const float* __restrict__ bias, void* __restrict__ Cout,
    int lda, int ldb, int ldc, int K,
    long long aBatch, long long bBatch, long long cBatch)
{
    constexpr int THREADS = WM * WN * 64;
    constexpr int WROWS = BM / WM, WCOLS = BN / WN;
    constexpr int MI = WROWS / 16, NI = WCOLS / 16;
    constexpr int ABYTES = BM * 64;
    constexpr int BBYTES = BN * 64;
    constexpr int BUF = ABYTES + BBYTES;

    __shared__ unsigned char smem[4 * BUF];

    const int tid  = threadIdx.x;
    const int lane = tid & 63;
    const int wave = tid >> 6;
    const int wr   = wave / WN;
    const int wc   = wave % WN;
    const int bz   = blockIdx.z;

    const int nx  = gridDim.x;
    const int bid = blockIdx.y * nx + blockIdx.x;
    const int cpx = (nx * gridDim.y) >> 3;
    const int swz = (bid & 7) * cpx + (bid >> 3);
    const long long m0 = (long long)(swz / nx) * BM;
    const long long n0 = (long long)(swz % nx) * BN;

    const bf16* Ab = A  + bz * aBatch + m0 * lda;
    const bf16* Bb = Bm + bz * bBatch + n0 * ldb;

    f32x4 acc[MI][NI] = {};
    const int NT = K >> 5;

    auto stage = [&](int t) {
        unsigned char* dst = smem + (t & 3) * BUF;
        const long long kk = (long long)t << 5;
        #pragma unroll
        for (int j = 0; j < 2; ++j) {
            const int g  = wave * 64 + lane + j * THREADS;
            const int gs = g ^ ((g >> 3) & 3);
            const int row = gs >> 2, col = (gs & 3) * 8;
            load_lds16(Ab + (long long)row * lda + kk + col,
                       dst + (wave * 64 + j * THREADS) * 16);
        }
        #pragma unroll
        for (int j = 0; j < 2; ++j) {
            const int g  = wave * 64 + lane + j * THREADS;
            const int gs = g ^ ((g >> 3) & 3);
            const int row = gs >> 2, col = (gs & 3) * 8;
            load_lds16(Bb + (long long)row * ldb + kk + col,
                       dst + ABYTES + (wave * 64 + j * THREADS) * 16);
        }
    };

    stage(0); stage(1); stage(2);

    const int ko2 = (lane >> 4) * 16;
    const int la15 = lane & 15;

    for (int t = 0; t < NT; ++t) {
        if (t + 2 < NT)      asm volatile("s_waitcnt vmcnt(8)" ::: "memory");
        else if (t + 1 < NT) asm volatile("s_waitcnt vmcnt(4)" ::: "memory");
        else                 asm volatile("s_waitcnt vmcnt(0)" ::: "memory");
        __builtin_amdgcn_s_barrier();
        asm volatile("" ::: "memory");

        if (t + 3 < NT) stage(t + 3);

        const unsigned char* buf = smem + (t & 3) * BUF;
        bf16x8 a[MI], b[NI];
        #pragma unroll
        for (int mi = 0; mi < MI; ++mi) {
            int ad = (wr * WROWS + mi * 16 + la15) * 64 + ko2;
            ad ^= ((ad >> 7) & 3) << 4;
            a[mi] = *(const bf16x8*)(buf + ad);
        }
        #pragma unroll
        for (int ni = 0; ni < NI; ++ni) {
            int ad = (wc * WCOLS + ni * 16 + la15) * 64 + ko2;
            ad ^= ((ad >> 7) & 3) << 4;
            b[ni] = *(const bf16x8*)(buf + ABYTES + ad);
        }

        __builtin_amdgcn_s_setprio(1);
        #pragma unroll
        for (int mi = 0; mi < MI; ++mi)
            #pragma unroll
            for (int ni = 0; ni < NI; ++ni)
                acc[mi][ni] = __builtin_amdgcn_mfma_f32_16x16x32_bf16(
                    a[mi], b[ni], acc[mi][ni], 0, 0, 0);
        __builtin_amdgcn_s_setprio(0);
    }

    const int crow = (lane >> 4) * 4;
    const int ccol = lane & 15;
    #pragma unroll
    for (int ni = 0; ni < NI; ++ni) {
        const long long c = n0 + wc * WCOLS + ni * 16 + ccol;
        float bcol = 0.0f;
        if (!BIASROW && bias) bcol = bias[c];
        #pragma unroll
        for (int mi = 0; mi < MI; ++mi) {
            const long long r0 = m0 + wr * WROWS + mi * 16 + crow;
            #pragma unroll
            for (int j = 0; j < 4; ++j) {
                float v = acc[mi][ni][j];
                v += BIASROW ? bias[r0 + j] : bcol;
                if (EPI == 1) v = (v > 0.0f) ? (v + 1.0f) : __expf(v);
                const long long idx = bz * cBatch + (r0 + j) * ldc + c;
                if (OUTF32) ((float*)Cout)[idx] = v;
                else        ((bf16*)Cout)[idx]  = (bf16)v;
            }
        }
    }
}

// ---------------- 256^2 8-phase GEMM, single barrier/phase ----------------
// EPI: 1 = elu+1; 2 = elu+1 iff m0<1024; 3 = rank-1 add (v += bias[row]*ksum[col]);
//      4 = elu+1 AND atomic row-sum into ksum[batch*D + row] (K-projection).
// ACCUM: bf16 path reads existing C and adds before store (KVo 2-pass).
// SPLITK: z = batch*SPLITK + kseg. GROUPN: 0 = A-reuse enum; 1 = B-reuse enum.
template<int EPI, int OUTF32, int BIASROW, int SPLITK, int GROUPN, int ACCUM>
__global__ __launch_bounds__(512, 1) void gemm8p(
    const bf16* __restrict__ A, const bf16* __restrict__ Bm,
    const float* __restrict__ bias, float* __restrict__ ksum,
    void* __restrict__ Cout,
    int lda, int ldb, int ldc, int K,
    long long aBatch, long long bBatch, long long cBatch)
{
    __shared__ unsigned char smem[131072];

    const int tid  = threadIdx.x;
    const int lane = tid & 63;
    const int wave = tid >> 6;
    const int wr   = wave >> 2;
    const int wc   = wave & 3;
    const int bz    = blockIdx.z;
    const int batch = bz / SPLITK;
    const int kseg  = bz % SPLITK;

    const int nx  = gridDim.x;
    const int ny  = gridDim.y;
    const int bid = blockIdx.y * nx + blockIdx.x;
    const int cpx = (nx * ny) >> 3;
    const int swzb = (bid & 7) * cpx + (bid >> 3);
    long long m0, n0;
    if (GROUPN) { n0 = (long long)(swzb / ny) * 256; m0 = (long long)(swzb % ny) * 256; }
    else        { m0 = (long long)(swzb / nx) * 256; n0 = (long long)(swzb % nx) * 256; }

    const bf16* Ab = A  + batch * aBatch + m0 * lda + (long long)kseg * K;
    const bf16* Bb = Bm + batch * bBatch + n0 * ldb + (long long)kseg * K;

    const int sg = (lane & 3) ^ ((lane >> 3) & 3);
    const long long srow = wave * 32 + (lane >> 2);
    const bf16* srcA  = Ab + srow * lda + sg * 8;
    const bf16* srcA2 = srcA + 16 * (long long)lda;
    const bf16* srcB  = Bb + srow * ldb + sg * 8;
    const bf16* srcB2 = srcB + 16 * (long long)ldb;
    const int dstoff = wave * 2048;

    const int la15 = lane & 15;
    const int rsw  = (lane >> 4) ^ ((la15 >> 1) & 3);
    const int a16  = (wr * 128 + la15) * 4 + rsw;
    const int b16  = (wc * 64  + la15) * 4 + rsw;

    f32x4 acc[8][4] = {};
    const int NT = K >> 6;
    const int NI = NT >> 1;

    auto stageA = [&](int T, int kh) {
        const int reg = ((((T & 1) << 1) | kh) << 14);
        const long long kp = ((long long)T << 6) + (kh << 5);
        load_lds16(srcA  + kp, smem + reg + dstoff);
        load_lds16(srcA2 + kp, smem + reg + dstoff + 1024);
    };
    auto stageB = [&](int T, int kh) {
        const int reg = 65536 + ((((T & 1) << 1) | kh) << 14);
        const long long kp = ((long long)T << 6) + (kh << 5);
        load_lds16(srcB  + kp, smem + reg + dstoff);
        load_lds16(srcB2 + kp, smem + reg + dstoff + 1024);
    };

    stageB(0, 0); stageA(0, 0); stageB(0, 1); stageA(0, 1);
    stageB(1, 0); stageA(1, 0); stageB(1, 1);
    asm volatile("s_waitcnt vmcnt(6)" ::: "memory");

    bf16x8 bfr[4];
    for (int i = 0; i < NI; ++i) {
        const int t = 2 * i;
        const bool nl = (i + 1 < NI);
        #pragma unroll
        for (int p = 0; p < 8; ++p) {
            const int ks  = (p >> 1) & 1;
            const int ch  = p & 1;
            const int buf = p >> 2;
            const int regA = ((buf << 1) | ks) << 14;
            const int regB = 65536 + regA;

            __builtin_amdgcn_s_barrier();
            __builtin_amdgcn_sched_barrier(0x10F);

            bf16x8 afr[4];
            if (ch == 0) {
                #pragma unroll
                for (int ni = 0; ni < 4; ++ni)
                    bfr[ni] = *(const bf16x8*)(smem + regB + (b16 + ni * 64) * 16);
            }
            #pragma unroll
            for (int m4 = 0; m4 < 4; ++m4)
                afr[m4] = *(const bf16x8*)(smem + regA + (a16 + (ch * 4 + m4) * 64) * 16);

            if      (p == 0) stageA(t + 1, 1);
            else if (p == 1) { if (t + 2 < NT) stageB(t + 2, 0); }
            else if (p == 2) { if (t + 2 < NT) stageA(t + 2, 0); }
            else if (p == 3) { if (t + 2 < NT) stageB(t + 2, 1); }
            else if (p == 4) { if (t + 2 < NT) stageA(t + 2, 1); }
            else if (p == 5) { if (t + 3 < NT) stageB(t + 3, 0); }
            else if (p == 6) { if (t + 3 < NT) stageA(t + 3, 0); }
            else             { if (t + 3 < NT) stageB(t + 3, 1); }

            if (p == 3) {
                if (nl) asm volatile("s_waitcnt vmcnt(6)" ::: "memory");
                else    asm volatile("s_waitcnt vmcnt(0)" ::: "memory");
            } else if (p == 7) {
                if (nl) asm volatile("s_waitcnt vmcnt(6)" ::: "memory");
            }

            __builtin_amdgcn_s_setprio(1);
            #pragma unroll
            for (int m4 = 0; m4 < 4; ++m4)
                #pragma unroll
                for (int ni = 0; ni < 4; ++ni)
                    acc[ch * 4 + m4][ni] = __builtin_amdgcn_mfma_f32_16x16x32_bf16(
                        afr[m4], bfr[ni], acc[ch * 4 + m4][ni], 0, 0, 0);
            __builtin_amdgcn_s_setprio(0);
        }
    }

    // ---- epilogue (all paths via LDS for contiguous stores) ----
    const bool doElu = (EPI == 1) || (EPI == 4) || (EPI == 2 && m0 < 1024);
    const long long cb = (long long)bz * cBatch;
    const int crow = (lane >> 4) * 4;

    if constexpr (OUTF32 != 0) {
        float* lt = (float*)smem;
        #pragma unroll
        for (int q = 0; q < 4; ++q) {
            __builtin_amdgcn_s_barrier();
            __builtin_amdgcn_sched_barrier(0);
            if (wr == (q >> 1)) {
                #pragma unroll
                for (int m4 = 0; m4 < 4; ++m4) {
                    const int mi = (q & 1) * 4 + m4;
                    const int lrow = m4 * 16 + crow;
                    const long long r0 = m0 + q * 64 + lrow;
                    #pragma unroll
                    for (int ni = 0; ni < 4; ++ni) {
                        const int lcol = wc * 64 + ni * 16 + la15;
                        float bb = 0.0f;
                        if (!BIASROW && bias) bb = bias[n0 + lcol];
                        #pragma unroll
                        for (int j = 0; j < 4; ++j) {
                            float v = acc[mi][ni][j] + (BIASROW ? bias[r0 + j] : bb);
                            if (doElu) v = (v > 0.0f) ? (v + 1.0f) : __expf(v);
                            lt[(lrow + j) * 260 + lcol] = v;
                        }
                    }
                }
            }
            __builtin_amdgcn_s_barrier();
            #pragma unroll
            for (int it = 0; it < 8; ++it) {
                const int chk = it * 512 + tid;
                const int r   = chk >> 6;
                const int g   = chk & 63;
                float4 v = *(const float4*)(lt + r * 260 + g * 4);
                *(float4*)((float*)Cout + cb + (m0 + q * 64 + r) * ldc + n0 + g * 4) = v;
            }
        }
    } else {
        bf16* lt = (bf16*)smem;
        #pragma unroll
        for (int half = 0; half < 2; ++half) {
            __builtin_amdgcn_s_barrier();
            __builtin_amdgcn_sched_barrier(0);
            if (wr == half) {
                #pragma unroll
                for (int mi = 0; mi < 8; ++mi) {
                    const int lrow = mi * 16 + crow;
                    const long long r0 = m0 + half * 128 + lrow;
                    #pragma unroll
                    for (int ni = 0; ni < 4; ++ni) {
                        const int lcol = wc * 64 + ni * 16 + la15;
                        float bb = 0.0f;
                        if (!BIASROW && bias) bb = bias[n0 + lcol];
                        float ksv = 0.0f;
                        if (EPI == 3 && ksum)
                            ksv = ksum[(long long)batch * D + n0 + lcol];
                        #pragma unroll
                        for (int j = 0; j < 4; ++j) {
                            float v;
                            if (EPI == 3) {
                                v = acc[mi][ni][j] + bias[r0 + j] * ksv;
                            } else {
                                v = acc[mi][ni][j] + (BIASROW ? bias[r0 + j] : bb);
                                if (doElu) v = (v > 0.0f) ? (v + 1.0f) : __expf(v);
                            }
                            lt[(lrow + j) * 264 + lcol] = (bf16)v;
                        }
                    }
                }
            }
            __builtin_amdgcn_s_barrier();
            #pragma unroll
            for (int it = 0; it < 8; ++it) {
                const int chk = it * 512 + tid;
                const int m   = chk >> 5;
                const int nof = (chk & 31) * 8;
                bf16x8 v = *(const bf16x8*)(lt + m * 264 + nof);
                bf16* cp = (bf16*)Cout + cb + (m0 + half * 128 + m) * ldc + n0 + nof;
                if constexpr (ACCUM != 0) {
                    bf16x8 old = *(const bf16x8*)cp;
                    #pragma unroll
                    for (int j = 0; j < 8; ++j)
                        v[j] = (bf16)((float)v[j] + (float)old[j]);
                }
                *(bf16x8*)cp = v;
            }
            if constexpr (EPI == 4) {
                // Ksum: per-row (d) partial sums of this half-tile's 256 cols (s)
                const int row = tid >> 2;             // 0..127
                const bf16* rp = lt + row * 264 + (tid & 3) * 64;
                float s = 0.0f;
                #pragma unroll
                for (int e8 = 0; e8 < 8; ++e8) {
                    bf16x8 v = *(const bf16x8*)(rp + e8 * 8);
                    #pragma unroll
                    for (int j = 0; j < 8; ++j) s += (float)v[j];
                }
                s += __shfl_down(s, 2);
                s += __shfl_down(s, 1);
                if ((tid & 3) == 0)
                    atomicAdd(ksum + (long long)batch * D + m0 + half * 128 + row, s);
            }
        }
    }
}

// ---------------- launch ----------------
extern "C" void kernel_launch(void* const* d_in, const int* in_sizes, int n_in,
                              void* d_out, int out_size, void* d_ws, size_t ws_size,
                              hipStream_t stream)
{
    const float* x  = (const float*)d_in[0];
    const float* Wq = (const float*)d_in[1];
    const float* bq = (const float*)d_in[2];
    const float* Wk = (const float*)d_in[3];
    const float* bk = (const float*)d_in[4];
    const float* Wv = (const float*)d_in[5];
    const float* bv = (const float*)d_in[6];
    const float* Wo = (const float*)d_in[7];
    const float* bo = (const float*)d_in[8];
    float* out = (float*)d_out;

    // ws layout (152 MiB):
    //  [0,64M)     xbp [b][s][f]
    //  [64M,96M)   M partials (16 x 2MB slabs: even = half0, odd = half1)
    //  [96M,96M+32K)  Ksum (fp32 8192)   [+32K,+36K) bvo  (both die before Qb)
    //  [64M,128M)  Qb (written after KVo gemms; clobbers partials/Ksum/bvo)
    //  [128M,144M) wvT temp (2MB, dead early) -> then KVo (16MB)
    //  [144M,152M) wqb | wob | wkb | Wvo  (2MB each)
    // d_out scratch: Kt [0,64M), xT [64M,128M) — both dead before final write.
    char* ws = (char*)d_ws;
    if (ws_size < (size_t)159383552) return;
    bf16*  xbp  = (bf16*)(ws + 0);
    bf16*  part = (bf16*)(ws + 67108864);
    bf16*  Qb   = (bf16*)(ws + 67108864);
    float* ks   = (float*)(ws + 100663296);
    float* bvo  = (float*)(ws + 100663296 + 32768);
    bf16*  wvT  = (bf16*)(ws + 134217728);
    bf16*  KVo  = (bf16*)(ws + 134217728);
    bf16*  wqb  = (bf16*)(ws + 150994944);
    bf16*  wob  = wqb + 1048576;
    bf16*  wkb  = wob + 1048576;
    bf16*  Wvo  = wkb + 1048576;
    bf16*  Kt   = (bf16*)d_out;            // [b][d][s]
    bf16*  xT   = Kt + NELEM;              // [b][f][s]

    const long long SD = (long long)S * D;
    const long long DD = (long long)D * D;

    // 1) converts + folded-weight prep (x permute + transpose fused, one pass)
    cvt_permute_both<<<dim3(64, 16, 8), 256, 0, stream>>>(x, xbp, xT);
    cvt_w3<<<dim3(1024, 3), 256, 0, stream>>>(Wq, Wo, Wk, wqb, wob, wkb);
    cvt_transpose_1024<<<dim3(16, 16), 256, 0, stream>>>(Wv, wvT);
    bvo_kernel<<<1024, 256, 0, stream>>>(Wo, bv, bvo);
    hipMemsetAsync(ks, 0, B * D * sizeof(float), stream);

    // 2) Wvo[e'][f] = sum_ve Wo[e'][ve] Wv[ve][f]  (A=wob, B=wvT)
    gemm_bt<128, 128, 2, 2, 0, 0, 0><<<dim3(8, 8, 1), 256, 0, stream>>>(
        wob, wvT, nullptr, Wvo, D, D, D, D, 0, 0, 0);

    // 3) K projection + fused Ksum: Kt[b][d][s] = elu(Wk xbp_b^T + bk)+1,
    //    ks[b][d] += row sums (atomic, 16 tiles contribute per row)
    gemm8p<4, 0, 1, 1, 1, 0><<<dim3(16, 4, 8), 512, 0, stream>>>(
        wkb, xbp, bk, ks, Kt, D, D, S, D, 0, SD, SD);

    // 4) M partials: part[2b+h][d][f] = sum_{s half h} Kt[b][d][s] xT[b][f][s]
    gemm8p<0, 0, 0, 2, 0, 0><<<dim3(4, 4, 16), 512, 0, stream>>>(
        Kt, xT, nullptr, nullptr, part, S, S, D, 2048, SD, SD, DD);

    // 5a) KVo[b][e'][d] = sum_f Wvo[e'][f] part[2b][d][f]            (write)
    gemm8p<0, 0, 0, 1, 0, 0><<<dim3(4, 4, 8), 512, 0, stream>>>(
        Wvo, part, nullptr, nullptr, KVo, D, D, D, D, 0, 2 * DD, DD);

    // 5b) KVo += sum_f Wvo[e'][f] part[2b+1][d][f] + bvo[e']*Ksum[b][d]  (accum)
    gemm8p<3, 0, 1, 1, 0, 1><<<dim3(4, 4, 8), 512, 0, stream>>>(
        Wvo, part + DD, bvo, ks, KVo, D, D, D, D, 0, 2 * DD, DD);

    // 6) Qb[b][s][d] = elu(xbp_b Wq^T + bq)+1  (clobbers partials/Ksum/bvo)
    gemm8p<1, 0, 0, 1, 0, 0><<<dim3(4, 16, 8), 512, 0, stream>>>(
        xbp, wqb, bq, nullptr, Qb, D, D, D, D, SD, 0, SD);

    // 7) out[s][b][e'] = Qb[b] @ KVo[b]^T + bo  (fp32; C row s at b*D offset)
    gemm8p<0, 1, 0, 1, 0, 0><<<dim3(4, 16, 8), 512, 0, stream>>>(
        Qb, KVo, bo, nullptr, out, D, D, B * D, D,
        SD, DD, (long long)D);
}

// Round 20
// 459.602 us; speedup vs baseline: 1.0459x; 1.0459x over previous
//
#include <hip/hip_runtime.h>

// LinearAttention, S=4096 B=8 D=1024.   (R18 configuration — session best 457.1us)
// Algebraic form: K = elu(Wk x^T + bk)+1 (only nonlinear proj materialized);
//   MT[b][d][f] = sum_s K[s,d] x[s,f];  KVo = Wvo*MT^T + bvo (x) Ksum;
//   out = (elu(x Wq^T + bq)+1) @ KVo^T + bo.   Wvo = Wo Wv, bvo = Wo bv.
// gemm8p: 256^2, 8 phases/iter, 1 barrier/phase, vmcnt(6)@P3/P7.

typedef __bf16 bf16;
typedef __attribute__((ext_vector_type(8))) __bf16 bf16x8;
typedef __attribute__((ext_vector_type(4))) __bf16 bf16x4;
typedef __attribute__((ext_vector_type(4))) float f32x4;

static constexpr int S = 4096;
static constexpr int B = 8;
static constexpr int D = 1024;
static constexpr int SB = S * B;
static constexpr long long NELEM = (long long)SB * D;
static constexpr int TP = 66;   // transpose tile row stride (bank-conflict-tuned)

__device__ __forceinline__ void load_lds16(const bf16* g, void* l)
{
    __builtin_amdgcn_global_load_lds(
        (const __attribute__((address_space(1))) void*)g,
        (__attribute__((address_space(3))) void*)l, 16, 0, 0);
}

// ---------------- 3x weight fp32 -> bf16 convert (merged) ----------------
__global__ void cvt_w3(const float* __restrict__ w0, const float* __restrict__ w1,
                       const float* __restrict__ w2, bf16* __restrict__ o0,
                       bf16* __restrict__ o1, bf16* __restrict__ o2)
{
    const float* in;
    bf16* out;
    if (blockIdx.y == 0)      { in = w0; out = o0; }
    else if (blockIdx.y == 1) { in = w1; out = o1; }
    else                      { in = w2; out = o2; }
    int i = (blockIdx.x * blockDim.x + threadIdx.x) * 4;
    float4 v = *(const float4*)(in + i);
    bf16x4 o;
    o[0] = (bf16)v.x; o[1] = (bf16)v.y; o[2] = (bf16)v.z; o[3] = (bf16)v.w;
    *(bf16x4*)(out + i) = o;
}

// ---- x [S][B][D] fp32 -> xbp [B][S][D] bf16 AND xT [B][D][S] bf16 (one pass) ----
__global__ __launch_bounds__(256) void cvt_permute_both(
    const float* __restrict__ in, bf16* __restrict__ xbp, bf16* __restrict__ xT)
{
    __shared__ bf16 tile[64 * TP];   // tile[f][s], stride TP=66
    const int b  = blockIdx.z;
    const int s0 = blockIdx.x * 64;
    const int f0 = blockIdx.y * 64;
    const int t  = threadIdx.x;
    const int rl = t >> 3;           // 0..31
    const int c8 = (t & 7) * 8;      // 0..56
    const long long SD = (long long)S * D;

    #pragma unroll
    for (int p = 0; p < 2; ++p) {
        const int r = rl + p * 32;   // s offset in tile
        const float* src = in + (long long)(s0 + r) * (B * D) + b * D + f0 + c8;
        float4 v0 = *(const float4*)(src);
        float4 v1 = *(const float4*)(src + 4);
        bf16x8 o;
        o[0] = (bf16)v0.x; o[1] = (bf16)v0.y; o[2] = (bf16)v0.z; o[3] = (bf16)v0.w;
        o[4] = (bf16)v1.x; o[5] = (bf16)v1.y; o[6] = (bf16)v1.z; o[7] = (bf16)v1.w;
        *(bf16x8*)(xbp + b * SD + (long long)(s0 + r) * D + f0 + c8) = o;
        #pragma unroll
        for (int j = 0; j < 8; ++j)
            tile[(c8 + j) * TP + r] = o[j];
    }
    __syncthreads();
    #pragma unroll
    for (int p = 0; p < 2; ++p) {
        const int fr = rl + p * 32;  // f offset in tile
        *(bf16x8*)(xT + b * SD + (long long)(f0 + fr) * S + s0 + c8) =
            *(const bf16x8*)(&tile[fr * TP + c8]);
    }
}

// ---------------- Wv (fp32 [e][d]) -> WvT (bf16 [d][e]) ----------------
__global__ __launch_bounds__(256) void cvt_transpose_1024(
    const float* __restrict__ in, bf16* __restrict__ out)
{
    __shared__ bf16 tile[64 * TP];   // tile[d][e], stride TP
    const int e0 = blockIdx.y * 64;
    const int d0 = blockIdx.x * 64;
    const int t  = threadIdx.x;
    const int rl = t >> 3;
    const int c8 = (t & 7) * 8;
    #pragma unroll
    for (int p = 0; p < 2; ++p) {
        int r = rl + p * 32;
        float4 v0 = *(const float4*)(in + (long long)(e0 + r) * D + d0 + c8);
        float4 v1 = *(const float4*)(in + (long long)(e0 + r) * D + d0 + c8 + 4);
        bf16x8 o;
        o[0] = (bf16)v0.x; o[1] = (bf16)v0.y; o[2] = (bf16)v0.z; o[3] = (bf16)v0.w;
        o[4] = (bf16)v1.x; o[5] = (bf16)v1.y; o[6] = (bf16)v1.z; o[7] = (bf16)v1.w;
        #pragma unroll
        for (int j = 0; j < 8; ++j)
            tile[(c8 + j) * TP + r] = o[j];
    }
    __syncthreads();
    #pragma unroll
    for (int p = 0; p < 2; ++p) {
        int dr = rl + p * 32;
        *(bf16x8*)(out + (long long)(d0 + dr) * D + e0 + c8) =
            *(const bf16x8*)(&tile[dr * TP + c8]);
    }
}

// ---------------- bvo = Wo @ bv (fp32) ----------------
__global__ __launch_bounds__(256) void bvo_kernel(
    const float* __restrict__ Wo, const float* __restrict__ bv, float* __restrict__ bvo)
{
    const int row = blockIdx.x;
    const int t = threadIdx.x;
    float4 w = *(const float4*)(Wo + (long long)row * D + t * 4);
    float4 b = *(const float4*)(bv + t * 4);
    float s = w.x*b.x + w.y*b.y + w.z*b.z + w.w*b.w;
    __shared__ float red[256];
    red[t] = s; __syncthreads();
    for (int off = 128; off > 0; off >>= 1) {
        if (t < off) red[t] += red[t + off];
        __syncthreads();
    }
    if (t == 0) bvo[row] = red[0];
}

// ---------------- MT[b] = part[2b] + part[2b+1], in-place into slab 2b ----------------
__global__ __launch_bounds__(256) void kv_add(bf16* __restrict__ p)
{
    const long long DD = (long long)D * D;
    const int b = blockIdx.y;
    const long long i = ((long long)blockIdx.x * 256 + threadIdx.x) * 8;
    bf16x8 u = *(const bf16x8*)(p + (2 * b) * DD + i);
    bf16x8 v = *(const bf16x8*)(p + (2 * b + 1) * DD + i);
    bf16x8 r;
    #pragma unroll
    for (int j = 0; j < 8; ++j) r[j] = (bf16)((float)u[j] + (float)v[j]);
    *(bf16x8*)(p + (2 * b) * DD + i) = r;   // same addr as u-read: race-free
}

// ---------------- R3 ring GEMM (small shapes: Wvo prep only) ----------------
template<int BM, int BN, int WM, int WN, int EPI, int OUTF32, int BIASROW>
__global__ __launch_bounds__(WM * WN * 64, 2) void gemm_bt(
    const bf16* __restrict__ A, const bf16* __restrict__ Bm,
    const float* __restrict__ bias, void* __restrict__ Cout,
    int lda, int ldb, int ldc, int K,
    long long aBatch, long long bBatch, long long cBatch)
{
    constexpr int THREADS = WM * WN * 64;
    constexpr int WROWS = BM / WM, WCOLS = BN / WN;
    constexpr int MI = WROWS / 16, NI = WCOLS / 16;
    constexpr int ABYTES = BM * 64;
    constexpr int BBYTES = BN * 64;
    constexpr int BUF = ABYTES + BBYTES;

    __shared__ unsigned char smem[4 * BUF];

    const int tid  = threadIdx.x;
    const int lane = tid & 63;
    const int wave = tid >> 6;
    const int wr   = wave / WN;
    const int wc   = wave % WN;
    const int bz   = blockIdx.z;

    const int nx  = gridDim.x;
    const int bid = blockIdx.y * nx + blockIdx.x;
    const int cpx = (nx * gridDim.y) >> 3;
    const int swz = (bid & 7) * cpx + (bid >> 3);
    const long long m0 = (long long)(swz / nx) * BM;
    const long long n0 = (long long)(swz % nx) * BN;

    const bf16* Ab = A  + bz * aBatch + m0 * lda;
    const bf16* Bb = Bm + bz * bBatch + n0 * ldb;

    f32x4 acc[MI][NI] = {};
    const int NT = K >> 5;

    auto stage = [&](int t) {
        unsigned char* dst = smem + (t & 3) * BUF;
        const long long kk = (long long)t << 5;
        #pragma unroll
        for (int j = 0; j < 2; ++j) {
            const int g  = wave * 64 + lane + j * THREADS;
            const int gs = g ^ ((g >> 3) & 3);
            const int row = gs >> 2, col = (gs & 3) * 8;
            load_lds16(Ab + (long long)row * lda + kk + col,
                       dst + (wave * 64 + j * THREADS) * 16);
        }
        #pragma unroll
        for (int j = 0; j < 2; ++j) {
            const int g  = wave * 64 + lane + j * THREADS;
            const int gs = g ^ ((g >> 3) & 3);
            const int row = gs >> 2, col = (gs & 3) * 8;
            load_lds16(Bb + (long long)row * ldb + kk + col,
                       dst + ABYTES + (wave * 64 + j * THREADS) * 16);
        }
    };

    stage(0); stage(1); stage(2);

    const int ko2 = (lane >> 4) * 16;
    const int la15 = lane & 15;

    for (int t = 0; t < NT; ++t) {
        if (t + 2 < NT)      asm volatile("s_waitcnt vmcnt(8)" ::: "memory");
        else if (t + 1 < NT) asm volatile("s_waitcnt vmcnt(4)" ::: "memory");
        else                 asm volatile("s_waitcnt vmcnt(0)" ::: "memory");
        __builtin_amdgcn_s_barrier();
        asm volatile("" ::: "memory");

        if (t + 3 < NT) stage(t + 3);

        const unsigned char* buf = smem + (t & 3) * BUF;
        bf16x8 a[MI], b[NI];
        #pragma unroll
        for (int mi = 0; mi < MI; ++mi) {
            int ad = (wr * WROWS + mi * 16 + la15) * 64 + ko2;
            ad ^= ((ad >> 7) & 3) << 4;
            a[mi] = *(const bf16x8*)(buf + ad);
        }
        #pragma unroll
        for (int ni = 0; ni < NI; ++ni) {
            int ad = (wc * WCOLS + ni * 16 + la15) * 64 + ko2;
            ad ^= ((ad >> 7) & 3) << 4;
            b[ni] = *(const bf16x8*)(buf + ABYTES + ad);
        }

        __builtin_amdgcn_s_setprio(1);
        #pragma unroll
        for (int mi = 0; mi < MI; ++mi)
            #pragma unroll
            for (int ni = 0; ni < NI; ++ni)
                acc[mi][ni] = __builtin_amdgcn_mfma_f32_16x16x32_bf16(
                    a[mi], b[ni], acc[mi][ni], 0, 0, 0);
        __builtin_amdgcn_s_setprio(0);
    }

    const int crow = (lane >> 4) * 4;
    const int ccol = lane & 15;
    #pragma unroll
    for (int ni = 0; ni < NI; ++ni) {
        const long long c = n0 + wc * WCOLS + ni * 16 + ccol;
        float bcol = 0.0f;
        if (!BIASROW && bias) bcol = bias[c];
        #pragma unroll
        for (int mi = 0; mi < MI; ++mi) {
            const long long r0 = m0 + wr * WROWS + mi * 16 + crow;
            #pragma unroll
            for (int j = 0; j < 4; ++j) {
                float v = acc[mi][ni][j];
                v += BIASROW ? bias[r0 + j] : bcol;
                if (EPI == 1) v = (v > 0.0f) ? (v + 1.0f) : __expf(v);
                const long long idx = bz * cBatch + (r0 + j) * ldc + c;
                if (OUTF32) ((float*)Cout)[idx] = v;
                else        ((bf16*)Cout)[idx]  = (bf16)v;
            }
        }
    }
}

// ---------------- 256^2 8-phase GEMM, single barrier/phase ----------------
// EPI: 1 = elu+1; 2 = elu+1 iff m0<1024; 3 = rank-1 add (v += bias[row]*ksum[col]);
//      4 = elu+1 AND atomic row-sum into ksum[batch*D + row] (K-projection).
// SPLITK: z = batch*SPLITK + kseg. GROUPN: 0 = A-reuse enum; 1 = B-reuse enum.
// Fence: sched_barrier(0x10F) — DS_READ/ALU/MFMA may cross; VMEM/DS-write pinned.
template<int EPI, int OUTF32, int BIASROW, int SPLITK, int GROUPN>
__global__ __launch_bounds__(512, 1) void gemm8p(
    const bf16* __restrict__ A, const bf16* __restrict__ Bm,
    const float* __restrict__ bias, float* __restrict__ ksum,
    void* __restrict__ Cout,
    int lda, int ldb, int ldc, int K,
    long long aBatch, long long bBatch, long long cBatch)
{
    __shared__ unsigned char smem[131072];

    const int tid  = threadIdx.x;
    const int lane = tid & 63;
    const int wave = tid >> 6;
    const int wr   = wave >> 2;
    const int wc   = wave & 3;
    const int bz    = blockIdx.z;
    const int batch = bz / SPLITK;
    const int kseg  = bz % SPLITK;

    const int nx  = gridDim.x;
    const int ny  = gridDim.y;
    const int bid = blockIdx.y * nx + blockIdx.x;
    const int cpx = (nx * ny) >> 3;
    const int swzb = (bid & 7) * cpx + (bid >> 3);
    long long m0, n0;
    if (GROUPN) { n0 = (long long)(swzb / ny) * 256; m0 = (long long)(swzb % ny) * 256; }
    else        { m0 = (long long)(swzb / nx) * 256; n0 = (long long)(swzb % nx) * 256; }

    const bf16* Ab = A  + batch * aBatch + m0 * lda + (long long)kseg * K;
    const bf16* Bb = Bm + batch * bBatch + n0 * ldb + (long long)kseg * K;

    const int sg = (lane & 3) ^ ((lane >> 3) & 3);
    const long long srow = wave * 32 + (lane >> 2);
    const bf16* srcA  = Ab + srow * lda + sg * 8;
    const bf16* srcA2 = srcA + 16 * (long long)lda;
    const bf16* srcB  = Bb + srow * ldb + sg * 8;
    const bf16* srcB2 = srcB + 16 * (long long)ldb;
    const int dstoff = wave * 2048;

    const int la15 = lane & 15;
    const int rsw  = (lane >> 4) ^ ((la15 >> 1) & 3);
    const int a16  = (wr * 128 + la15) * 4 + rsw;
    const int b16  = (wc * 64  + la15) * 4 + rsw;

    f32x4 acc[8][4] = {};
    const int NT = K >> 6;
    const int NI = NT >> 1;

    auto stageA = [&](int T, int kh) {
        const int reg = ((((T & 1) << 1) | kh) << 14);
        const long long kp = ((long long)T << 6) + (kh << 5);
        load_lds16(srcA  + kp, smem + reg + dstoff);
        load_lds16(srcA2 + kp, smem + reg + dstoff + 1024);
    };
    auto stageB = [&](int T, int kh) {
        const int reg = 65536 + ((((T & 1) << 1) | kh) << 14);
        const long long kp = ((long long)T << 6) + (kh << 5);
        load_lds16(srcB  + kp, smem + reg + dstoff);
        load_lds16(srcB2 + kp, smem + reg + dstoff + 1024);
    };

    stageB(0, 0); stageA(0, 0); stageB(0, 1); stageA(0, 1);
    stageB(1, 0); stageA(1, 0); stageB(1, 1);
    asm volatile("s_waitcnt vmcnt(6)" ::: "memory");

    bf16x8 bfr[4];
    for (int i = 0; i < NI; ++i) {
        const int t = 2 * i;
        const bool nl = (i + 1 < NI);
        #pragma unroll
        for (int p = 0; p < 8; ++p) {
            const int ks  = (p >> 1) & 1;
            const int ch  = p & 1;
            const int buf = p >> 2;
            const int regA = ((buf << 1) | ks) << 14;
            const int regB = 65536 + regA;

            __builtin_amdgcn_s_barrier();
            // permissive fence: DS_READ/ALU/MFMA may cross; VMEM & DS-write pinned
            __builtin_amdgcn_sched_barrier(0x10F);

            bf16x8 afr[4];
            if (ch == 0) {
                #pragma unroll
                for (int ni = 0; ni < 4; ++ni)
                    bfr[ni] = *(const bf16x8*)(smem + regB + (b16 + ni * 64) * 16);
            }
            #pragma unroll
            for (int m4 = 0; m4 < 4; ++m4)
                afr[m4] = *(const bf16x8*)(smem + regA + (a16 + (ch * 4 + m4) * 64) * 16);

            if      (p == 0) stageA(t + 1, 1);
            else if (p == 1) { if (t + 2 < NT) stageB(t + 2, 0); }
            else if (p == 2) { if (t + 2 < NT) stageA(t + 2, 0); }
            else if (p == 3) { if (t + 2 < NT) stageB(t + 2, 1); }
            else if (p == 4) { if (t + 2 < NT) stageA(t + 2, 1); }
            else if (p == 5) { if (t + 3 < NT) stageB(t + 3, 0); }
            else if (p == 6) { if (t + 3 < NT) stageA(t + 3, 0); }
            else             { if (t + 3 < NT) stageB(t + 3, 1); }

            if (p == 3) {
                if (nl) asm volatile("s_waitcnt vmcnt(6)" ::: "memory");
                else    asm volatile("s_waitcnt vmcnt(0)" ::: "memory");
            } else if (p == 7) {
                if (nl) asm volatile("s_waitcnt vmcnt(6)" ::: "memory");
            }

            __builtin_amdgcn_s_setprio(1);
            #pragma unroll
            for (int m4 = 0; m4 < 4; ++m4)
                #pragma unroll
                for (int ni = 0; ni < 4; ++ni)
                    acc[ch * 4 + m4][ni] = __builtin_amdgcn_mfma_f32_16x16x32_bf16(
                        afr[m4], bfr[ni], acc[ch * 4 + m4][ni], 0, 0, 0);
            __builtin_amdgcn_s_setprio(0);
        }
    }

    // ---- epilogue (all paths via LDS for contiguous stores) ----
    const bool doElu = (EPI == 1) || (EPI == 4) || (EPI == 2 && m0 < 1024);
    const long long cb = (long long)bz * cBatch;
    const int crow = (lane >> 4) * 4;

    if constexpr (OUTF32 != 0) {
        float* lt = (float*)smem;
        #pragma unroll
        for (int q = 0; q < 4; ++q) {
            __builtin_amdgcn_s_barrier();
            __builtin_amdgcn_sched_barrier(0);
            if (wr == (q >> 1)) {
                #pragma unroll
                for (int m4 = 0; m4 < 4; ++m4) {
                    const int mi = (q & 1) * 4 + m4;
                    const int lrow = m4 * 16 + crow;
                    const long long r0 = m0 + q * 64 + lrow;
                    #pragma unroll
                    for (int ni = 0; ni < 4; ++ni) {
                        const int lcol = wc * 64 + ni * 16 + la15;
                        float bb = 0.0f;
                        if (!BIASROW && bias) bb = bias[n0 + lcol];
                        #pragma unroll
                        for (int j = 0; j < 4; ++j) {
                            float v = acc[mi][ni][j] + (BIASROW ? bias[r0 + j] : bb);
                            if (doElu) v = (v > 0.0f) ? (v + 1.0f) : __expf(v);
                            lt[(lrow + j) * 260 + lcol] = v;
                        }
                    }
                }
            }
            __builtin_amdgcn_s_barrier();
            #pragma unroll
            for (int it = 0; it < 8; ++it) {
                const int chk = it * 512 + tid;
                const int r   = chk >> 6;
                const int g   = chk & 63;
                float4 v = *(const float4*)(lt + r * 260 + g * 4);
                *(float4*)((float*)Cout + cb + (m0 + q * 64 + r) * ldc + n0 + g * 4) = v;
            }
        }
    } else {
        bf16* lt = (bf16*)smem;
        #pragma unroll
        for (int half = 0; half < 2; ++half) {
            __builtin_amdgcn_s_barrier();
            __builtin_amdgcn_sched_barrier(0);
            if (wr == half) {
                #pragma unroll
                for (int mi = 0; mi < 8; ++mi) {
                    const int lrow = mi * 16 + crow;
                    const long long r0 = m0 + half * 128 + lrow;
                    #pragma unroll
                    for (int ni = 0; ni < 4; ++ni) {
                        const int lcol = wc * 64 + ni * 16 + la15;
                        float bb = 0.0f;
                        if (!BIASROW && bias) bb = bias[n0 + lcol];
                        float ksv = 0.0f;
                        if (EPI == 3 && ksum)
                            ksv = ksum[(long long)batch * D + n0 + lcol];
                        #pragma unroll
                        for (int j = 0; j < 4; ++j) {
                            float v;
                            if (EPI == 3) {
                                v = acc[mi][ni][j] + bias[r0 + j] * ksv;
                            } else {
                                v = acc[mi][ni][j] + (BIASROW ? bias[r0 + j] : bb);
                                if (doElu) v = (v > 0.0f) ? (v + 1.0f) : __expf(v);
                            }
                            lt[(lrow + j) * 264 + lcol] = (bf16)v;
                        }
                    }
                }
            }
            __builtin_amdgcn_s_barrier();
            #pragma unroll
            for (int it = 0; it < 8; ++it) {
                const int chk = it * 512 + tid;
                const int m   = chk >> 5;
                const int nof = (chk & 31) * 8;
                bf16x8 v = *(const bf16x8*)(lt + m * 264 + nof);
                *(bf16x8*)((bf16*)Cout + cb + (m0 + half * 128 + m) * ldc + n0 + nof) = v;
            }
            if constexpr (EPI == 4) {
                // Ksum: per-row (d) partial sums of this half-tile's 256 cols (s)
                const int row = tid >> 2;             // 0..127
                const bf16* rp = lt + row * 264 + (tid & 3) * 64;
                float s = 0.0f;
                #pragma unroll
                for (int e8 = 0; e8 < 8; ++e8) {
                    bf16x8 v = *(const bf16x8*)(rp + e8 * 8);
                    #pragma unroll
                    for (int j = 0; j < 8; ++j) s += (float)v[j];
                }
                s += __shfl_down(s, 2);
                s += __shfl_down(s, 1);
                if ((tid & 3) == 0)
                    atomicAdd(ksum + (long long)batch * D + m0 + half * 128 + row, s);
            }
        }
    }
}

// ---------------- launch ----------------
extern "C" void kernel_launch(void* const* d_in, const int* in_sizes, int n_in,
                              void* d_out, int out_size, void* d_ws, size_t ws_size,
                              hipStream_t stream)
{
    const float* x  = (const float*)d_in[0];
    const float* Wq = (const float*)d_in[1];
    const float* bq = (const float*)d_in[2];
    const float* Wk = (const float*)d_in[3];
    const float* bk = (const float*)d_in[4];
    const float* Wv = (const float*)d_in[5];
    const float* bv = (const float*)d_in[6];
    const float* Wo = (const float*)d_in[7];
    const float* bo = (const float*)d_in[8];
    float* out = (float*)d_out;

    // ws layout (152 MiB):
    //  [0,64M)     xbp [b][s][f]
    //  [64M,96M)   M partials (16 x 2MB slabs) -> MT in even slabs -> then Qb
    //  [96M,96M+32K)  Ksum (fp32 8192)   [+32K,+36K) bvo  (both die before Qb)
    //  [64M,128M)  Qb (written after KVo-gemm; clobbers partials/Ksum/bvo)
    //  [128M,144M) wvT temp (2MB, dead early) -> then KVo (16MB)
    //  [144M,152M) wqb | wob | wkb | Wvo  (2MB each)
    // d_out scratch: Kt [0,64M), xT [64M,128M) — both dead before final write.
    char* ws = (char*)d_ws;
    if (ws_size < (size_t)159383552) return;
    bf16*  xbp  = (bf16*)(ws + 0);
    bf16*  part = (bf16*)(ws + 67108864);
    bf16*  Qb   = (bf16*)(ws + 67108864);
    float* ks   = (float*)(ws + 100663296);
    float* bvo  = (float*)(ws + 100663296 + 32768);
    bf16*  wvT  = (bf16*)(ws + 134217728);
    bf16*  KVo  = (bf16*)(ws + 134217728);
    bf16*  wqb  = (bf16*)(ws + 150994944);
    bf16*  wob  = wqb + 1048576;
    bf16*  wkb  = wob + 1048576;
    bf16*  Wvo  = wkb + 1048576;
    bf16*  Kt   = (bf16*)d_out;            // [b][d][s]
    bf16*  xT   = Kt + NELEM;              // [b][f][s]

    const long long SD = (long long)S * D;
    const long long DD = (long long)D * D;

    // 1) converts + folded-weight prep (x permute + transpose fused, one pass)
    cvt_permute_both<<<dim3(64, 16, 8), 256, 0, stream>>>(x, xbp, xT);
    cvt_w3<<<dim3(1024, 3), 256, 0, stream>>>(Wq, Wo, Wk, wqb, wob, wkb);
    cvt_transpose_1024<<<dim3(16, 16), 256, 0, stream>>>(Wv, wvT);
    bvo_kernel<<<1024, 256, 0, stream>>>(Wo, bv, bvo);
    hipMemsetAsync(ks, 0, B * D * sizeof(float), stream);

    // 2) Wvo[e'][f] = sum_ve Wo[e'][ve] Wv[ve][f]  (A=wob, B=wvT)
    gemm_bt<128, 128, 2, 2, 0, 0, 0><<<dim3(8, 8, 1), 256, 0, stream>>>(
        wob, wvT, nullptr, Wvo, D, D, D, D, 0, 0, 0);

    // 3) K projection + fused Ksum: Kt[b][d][s] = elu(Wk xbp_b^T + bk)+1,
    //    ks[b][d] += row sums (atomic, 16 tiles contribute per row)
    gemm8p<4, 0, 1, 1, 1><<<dim3(16, 4, 8), 512, 0, stream>>>(
        wkb, xbp, bk, ks, Kt, D, D, S, D, 0, SD, SD);

    // 4) M partials: part[2b+h][d][f] = sum_{s half h} Kt[b][d][s] xT[b][f][s]
    gemm8p<0, 0, 0, 2, 0><<<dim3(4, 4, 16), 512, 0, stream>>>(
        Kt, xT, nullptr, nullptr, part, S, S, D, 2048, SD, SD, DD);

    // 5) MT[b] = part[2b] + part[2b+1]  (in-place into even slabs)
    kv_add<<<dim3(512, 8), 256, 0, stream>>>(part);

    // 6) KVo[b][e'][d] = sum_f Wvo[e'][f] MT[b][d][f] + bvo[e']*Ksum[b][d]
    gemm8p<3, 0, 1, 1, 0><<<dim3(4, 4, 8), 512, 0, stream>>>(
        Wvo, part, bvo, ks, KVo, D, D, D, D, 0, 2 * DD, DD);

    // 7) Qb[b][s][d] = elu(xbp_b Wq^T + bq)+1  (clobbers partials/Ksum/bvo)
    gemm8p<1, 0, 0, 1, 0><<<dim3(4, 16, 8), 512, 0, stream>>>(
        xbp, wqb, bq, nullptr, Qb, D, D, D, D, SD, 0, SD);

    // 8) out[s][b][e'] = Qb[b] @ KVo[b]^T + bo  (fp32; C row s at b*D offset)
    gemm8p<0, 1, 0, 1, 0><<<dim3(4, 16, 8), 512, 0, stream>>>(
        Qb, KVo, bo, nullptr, out, D, D, B * D, D,
        SD, DD, (long long)D);
}

// Round 21
// 458.538 us; speedup vs baseline: 1.0483x; 1.0023x over previous
//
#include <hip/hip_runtime.h>

// LinearAttention, S=4096 B=8 D=1024.   (final: R18 config + TP=65 transpose pad)
// Algebraic form: K = elu(Wk x^T + bk)+1 (only nonlinear proj materialized);
//   MT[b][d][f] = sum_s K[s,d] x[s,f];  KVo = Wvo*MT^T + bvo (x) Ksum;
//   out = (elu(x Wq^T + bq)+1) @ KVo^T + bo.   Wvo = Wo Wv, bvo = Wo bv.
// gemm8p: 256^2, 8 phases/iter, 1 barrier/phase, vmcnt(6)@P3/P7.

typedef __bf16 bf16;
typedef __attribute__((ext_vector_type(8))) __bf16 bf16x8;
typedef __attribute__((ext_vector_type(4))) __bf16 bf16x4;
typedef __attribute__((ext_vector_type(4))) float f32x4;

static constexpr int S = 4096;
static constexpr int B = 8;
static constexpr int D = 1024;
static constexpr int SB = S * B;
static constexpr long long NELEM = (long long)SB * D;
static constexpr int TP = 65;   // transpose tile row stride: scalar writes conflict-free

__device__ __forceinline__ void load_lds16(const bf16* g, void* l)
{
    __builtin_amdgcn_global_load_lds(
        (const __attribute__((address_space(1))) void*)g,
        (__attribute__((address_space(3))) void*)l, 16, 0, 0);
}

// ---------------- 3x weight fp32 -> bf16 convert (merged) ----------------
__global__ void cvt_w3(const float* __restrict__ w0, const float* __restrict__ w1,
                       const float* __restrict__ w2, bf16* __restrict__ o0,
                       bf16* __restrict__ o1, bf16* __restrict__ o2)
{
    const float* in;
    bf16* out;
    if (blockIdx.y == 0)      { in = w0; out = o0; }
    else if (blockIdx.y == 1) { in = w1; out = o1; }
    else                      { in = w2; out = o2; }
    int i = (blockIdx.x * blockDim.x + threadIdx.x) * 4;
    float4 v = *(const float4*)(in + i);
    bf16x4 o;
    o[0] = (bf16)v.x; o[1] = (bf16)v.y; o[2] = (bf16)v.z; o[3] = (bf16)v.w;
    *(bf16x4*)(out + i) = o;
}

// ---- x [S][B][D] fp32 -> xbp [B][S][D] bf16 AND xT [B][D][S] bf16 (one pass) ----
__global__ __launch_bounds__(256) void cvt_permute_both(
    const float* __restrict__ in, bf16* __restrict__ xbp, bf16* __restrict__ xT)
{
    __shared__ bf16 tile[64 * TP];   // tile[f][s], stride TP=65
    const int b  = blockIdx.z;
    const int s0 = blockIdx.x * 64;
    const int f0 = blockIdx.y * 64;
    const int t  = threadIdx.x;
    const int rl = t >> 3;           // 0..31
    const int c8 = (t & 7) * 8;      // 0..56
    const long long SD = (long long)S * D;

    #pragma unroll
    for (int p = 0; p < 2; ++p) {
        const int r = rl + p * 32;   // s offset in tile
        const float* src = in + (long long)(s0 + r) * (B * D) + b * D + f0 + c8;
        float4 v0 = *(const float4*)(src);
        float4 v1 = *(const float4*)(src + 4);
        bf16x8 o;
        o[0] = (bf16)v0.x; o[1] = (bf16)v0.y; o[2] = (bf16)v0.z; o[3] = (bf16)v0.w;
        o[4] = (bf16)v1.x; o[5] = (bf16)v1.y; o[6] = (bf16)v1.z; o[7] = (bf16)v1.w;
        *(bf16x8*)(xbp + b * SD + (long long)(s0 + r) * D + f0 + c8) = o;
        #pragma unroll
        for (int j = 0; j < 8; ++j)
            tile[(c8 + j) * TP + r] = o[j];
    }
    __syncthreads();
    #pragma unroll
    for (int p = 0; p < 2; ++p) {
        const int fr = rl + p * 32;  // f offset in tile
        *(bf16x8*)(xT + b * SD + (long long)(f0 + fr) * S + s0 + c8) =
            *(const bf16x8*)(&tile[fr * TP + c8]);
    }
}

// ---------------- Wv (fp32 [e][d]) -> WvT (bf16 [d][e]) ----------------
__global__ __launch_bounds__(256) void cvt_transpose_1024(
    const float* __restrict__ in, bf16* __restrict__ out)
{
    __shared__ bf16 tile[64 * TP];   // tile[d][e], stride TP
    const int e0 = blockIdx.y * 64;
    const int d0 = blockIdx.x * 64;
    const int t  = threadIdx.x;
    const int rl = t >> 3;
    const int c8 = (t & 7) * 8;
    #pragma unroll
    for (int p = 0; p < 2; ++p) {
        int r = rl + p * 32;
        float4 v0 = *(const float4*)(in + (long long)(e0 + r) * D + d0 + c8);
        float4 v1 = *(const float4*)(in + (long long)(e0 + r) * D + d0 + c8 + 4);
        bf16x8 o;
        o[0] = (bf16)v0.x; o[1] = (bf16)v0.y; o[2] = (bf16)v0.z; o[3] = (bf16)v0.w;
        o[4] = (bf16)v1.x; o[5] = (bf16)v1.y; o[6] = (bf16)v1.z; o[7] = (bf16)v1.w;
        #pragma unroll
        for (int j = 0; j < 8; ++j)
            tile[(c8 + j) * TP + r] = o[j];
    }
    __syncthreads();
    #pragma unroll
    for (int p = 0; p < 2; ++p) {
        int dr = rl + p * 32;
        *(bf16x8*)(out + (long long)(d0 + dr) * D + e0 + c8) =
            *(const bf16x8*)(&tile[dr * TP + c8]);
    }
}

// ---------------- bvo = Wo @ bv (fp32) ----------------
__global__ __launch_bounds__(256) void bvo_kernel(
    const float* __restrict__ Wo, const float* __restrict__ bv, float* __restrict__ bvo)
{
    const int row = blockIdx.x;
    const int t = threadIdx.x;
    float4 w = *(const float4*)(Wo + (long long)row * D + t * 4);
    float4 b = *(const float4*)(bv + t * 4);
    float s = w.x*b.x + w.y*b.y + w.z*b.z + w.w*b.w;
    __shared__ float red[256];
    red[t] = s; __syncthreads();
    for (int off = 128; off > 0; off >>= 1) {
        if (t < off) red[t] += red[t + off];
        __syncthreads();
    }
    if (t == 0) bvo[row] = red[0];
}

// ---------------- MT[b] = part[2b] + part[2b+1], in-place into slab 2b ----------------
__global__ __launch_bounds__(256) void kv_add(bf16* __restrict__ p)
{
    const long long DD = (long long)D * D;
    const int b = blockIdx.y;
    const long long i = ((long long)blockIdx.x * 256 + threadIdx.x) * 8;
    bf16x8 u = *(const bf16x8*)(p + (2 * b) * DD + i);
    bf16x8 v = *(const bf16x8*)(p + (2 * b + 1) * DD + i);
    bf16x8 r;
    #pragma unroll
    for (int j = 0; j < 8; ++j) r[j] = (bf16)((float)u[j] + (float)v[j]);
    *(bf16x8*)(p + (2 * b) * DD + i) = r;   // same addr as u-read: race-free
}

// ---------------- R3 ring GEMM (small shapes: Wvo prep only) ----------------
template<int BM, int BN, int WM, int WN, int EPI, int OUTF32, int BIASROW>
__global__ __launch_bounds__(WM * WN * 64, 2) void gemm_bt(
    const bf16* __restrict__ A, const bf16* __restrict__ Bm,
    const float* __restrict__ bias, void* __restrict__ Cout,
    int lda, int ldb, int ldc, int K,
    long long aBatch, long long bBatch, long long cBatch)
{
    constexpr int THREADS = WM * WN * 64;
    constexpr int WROWS = BM / WM, WCOLS = BN / WN;
    constexpr int MI = WROWS / 16, NI = WCOLS / 16;
    constexpr int ABYTES = BM * 64;
    constexpr int BBYTES = BN * 64;
    constexpr int BUF = ABYTES + BBYTES;

    __shared__ unsigned char smem[4 * BUF];

    const int tid  = threadIdx.x;
    const int lane = tid & 63;
    const int wave = tid >> 6;
    const int wr   = wave / WN;
    const int wc   = wave % WN;
    const int bz   = blockIdx.z;

    const int nx  = gridDim.x;
    const int bid = blockIdx.y * nx + blockIdx.x;
    const int cpx = (nx * gridDim.y) >> 3;
    const int swz = (bid & 7) * cpx + (bid >> 3);
    const long long m0 = (long long)(swz / nx) * BM;
    const long long n0 = (long long)(swz % nx) * BN;

    const bf16* Ab = A  + bz * aBatch + m0 * lda;
    const bf16* Bb = Bm + bz * bBatch + n0 * ldb;

    f32x4 acc[MI][NI] = {};
    const int NT = K >> 5;

    auto stage = [&](int t) {
        unsigned char* dst = smem + (t & 3) * BUF;
        const long long kk = (long long)t << 5;
        #pragma unroll
        for (int j = 0; j < 2; ++j) {
            const int g  = wave * 64 + lane + j * THREADS;
            const int gs = g ^ ((g >> 3) & 3);
            const int row = gs >> 2, col = (gs & 3) * 8;
            load_lds16(Ab + (long long)row * lda + kk + col,
                       dst + (wave * 64 + j * THREADS) * 16);
        }
        #pragma unroll
        for (int j = 0; j < 2; ++j) {
            const int g  = wave * 64 + lane + j * THREADS;
            const int gs = g ^ ((g >> 3) & 3);
            const int row = gs >> 2, col = (gs & 3) * 8;
            load_lds16(Bb + (long long)row * ldb + kk + col,
                       dst + ABYTES + (wave * 64 + j * THREADS) * 16);
        }
    };

    stage(0); stage(1); stage(2);

    const int ko2 = (lane >> 4) * 16;
    const int la15 = lane & 15;

    for (int t = 0; t < NT; ++t) {
        if (t + 2 < NT)      asm volatile("s_waitcnt vmcnt(8)" ::: "memory");
        else if (t + 1 < NT) asm volatile("s_waitcnt vmcnt(4)" ::: "memory");
        else                 asm volatile("s_waitcnt vmcnt(0)" ::: "memory");
        __builtin_amdgcn_s_barrier();
        asm volatile("" ::: "memory");

        if (t + 3 < NT) stage(t + 3);

        const unsigned char* buf = smem + (t & 3) * BUF;
        bf16x8 a[MI], b[NI];
        #pragma unroll
        for (int mi = 0; mi < MI; ++mi) {
            int ad = (wr * WROWS + mi * 16 + la15) * 64 + ko2;
            ad ^= ((ad >> 7) & 3) << 4;
            a[mi] = *(const bf16x8*)(buf + ad);
        }
        #pragma unroll
        for (int ni = 0; ni < NI; ++ni) {
            int ad = (wc * WCOLS + ni * 16 + la15) * 64 + ko2;
            ad ^= ((ad >> 7) & 3) << 4;
            b[ni] = *(const bf16x8*)(buf + ABYTES + ad);
        }

        __builtin_amdgcn_s_setprio(1);
        #pragma unroll
        for (int mi = 0; mi < MI; ++mi)
            #pragma unroll
            for (int ni = 0; ni < NI; ++ni)
                acc[mi][ni] = __builtin_amdgcn_mfma_f32_16x16x32_bf16(
                    a[mi], b[ni], acc[mi][ni], 0, 0, 0);
        __builtin_amdgcn_s_setprio(0);
    }

    const int crow = (lane >> 4) * 4;
    const int ccol = lane & 15;
    #pragma unroll
    for (int ni = 0; ni < NI; ++ni) {
        const long long c = n0 + wc * WCOLS + ni * 16 + ccol;
        float bcol = 0.0f;
        if (!BIASROW && bias) bcol = bias[c];
        #pragma unroll
        for (int mi = 0; mi < MI; ++mi) {
            const long long r0 = m0 + wr * WROWS + mi * 16 + crow;
            #pragma unroll
            for (int j = 0; j < 4; ++j) {
                float v = acc[mi][ni][j];
                v += BIASROW ? bias[r0 + j] : bcol;
                if (EPI == 1) v = (v > 0.0f) ? (v + 1.0f) : __expf(v);
                const long long idx = bz * cBatch + (r0 + j) * ldc + c;
                if (OUTF32) ((float*)Cout)[idx] = v;
                else        ((bf16*)Cout)[idx]  = (bf16)v;
            }
        }
    }
}

// ---------------- 256^2 8-phase GEMM, single barrier/phase ----------------
// EPI: 1 = elu+1; 2 = elu+1 iff m0<1024; 3 = rank-1 add (v += bias[row]*ksum[col]);
//      4 = elu+1 AND atomic row-sum into ksum[batch*D + row] (K-projection).
// SPLITK: z = batch*SPLITK + kseg. GROUPN: 0 = A-reuse enum; 1 = B-reuse enum.
// Fence: sched_barrier(0x10F) — DS_READ/ALU/MFMA may cross; VMEM/DS-write pinned.
template<int EPI, int OUTF32, int BIASROW, int SPLITK, int GROUPN>
__global__ __launch_bounds__(512, 1) void gemm8p(
    const bf16* __restrict__ A, const bf16* __restrict__ Bm,
    const float* __restrict__ bias, float* __restrict__ ksum,
    void* __restrict__ Cout,
    int lda, int ldb, int ldc, int K,
    long long aBatch, long long bBatch, long long cBatch)
{
    __shared__ unsigned char smem[131072];

    const int tid  = threadIdx.x;
    const int lane = tid & 63;
    const int wave = tid >> 6;
    const int wr   = wave >> 2;
    const int wc   = wave & 3;
    const int bz    = blockIdx.z;
    const int batch = bz / SPLITK;
    const int kseg  = bz % SPLITK;

    const int nx  = gridDim.x;
    const int ny  = gridDim.y;
    const int bid = blockIdx.y * nx + blockIdx.x;
    const int cpx = (nx * ny) >> 3;
    const int swzb = (bid & 7) * cpx + (bid >> 3);
    long long m0, n0;
    if (GROUPN) { n0 = (long long)(swzb / ny) * 256; m0 = (long long)(swzb % ny) * 256; }
    else        { m0 = (long long)(swzb / nx) * 256; n0 = (long long)(swzb % nx) * 256; }

    const bf16* Ab = A  + batch * aBatch + m0 * lda + (long long)kseg * K;
    const bf16* Bb = Bm + batch * bBatch + n0 * ldb + (long long)kseg * K;

    const int sg = (lane & 3) ^ ((lane >> 3) & 3);
    const long long srow = wave * 32 + (lane >> 2);
    const bf16* srcA  = Ab + srow * lda + sg * 8;
    const bf16* srcA2 = srcA + 16 * (long long)lda;
    const bf16* srcB  = Bb + srow * ldb + sg * 8;
    const bf16* srcB2 = srcB + 16 * (long long)ldb;
    const int dstoff = wave * 2048;

    const int la15 = lane & 15;
    const int rsw  = (lane >> 4) ^ ((la15 >> 1) & 3);
    const int a16  = (wr * 128 + la15) * 4 + rsw;
    const int b16  = (wc * 64  + la15) * 4 + rsw;

    f32x4 acc[8][4] = {};
    const int NT = K >> 6;
    const int NI = NT >> 1;

    auto stageA = [&](int T, int kh) {
        const int reg = ((((T & 1) << 1) | kh) << 14);
        const long long kp = ((long long)T << 6) + (kh << 5);
        load_lds16(srcA  + kp, smem + reg + dstoff);
        load_lds16(srcA2 + kp, smem + reg + dstoff + 1024);
    };
    auto stageB = [&](int T, int kh) {
        const int reg = 65536 + ((((T & 1) << 1) | kh) << 14);
        const long long kp = ((long long)T << 6) + (kh << 5);
        load_lds16(srcB  + kp, smem + reg + dstoff);
        load_lds16(srcB2 + kp, smem + reg + dstoff + 1024);
    };

    stageB(0, 0); stageA(0, 0); stageB(0, 1); stageA(0, 1);
    stageB(1, 0); stageA(1, 0); stageB(1, 1);
    asm volatile("s_waitcnt vmcnt(6)" ::: "memory");

    bf16x8 bfr[4];
    for (int i = 0; i < NI; ++i) {
        const int t = 2 * i;
        const bool nl = (i + 1 < NI);
        #pragma unroll
        for (int p = 0; p < 8; ++p) {
            const int ks  = (p >> 1) & 1;
            const int ch  = p & 1;
            const int buf = p >> 2;
            const int regA = ((buf << 1) | ks) << 14;
            const int regB = 65536 + regA;

            __builtin_amdgcn_s_barrier();
            // permissive fence: DS_READ/ALU/MFMA may cross; VMEM & DS-write pinned
            __builtin_amdgcn_sched_barrier(0x10F);

            bf16x8 afr[4];
            if (ch == 0) {
                #pragma unroll
                for (int ni = 0; ni < 4; ++ni)
                    bfr[ni] = *(const bf16x8*)(smem + regB + (b16 + ni * 64) * 16);
            }
            #pragma unroll
            for (int m4 = 0; m4 < 4; ++m4)
                afr[m4] = *(const bf16x8*)(smem + regA + (a16 + (ch * 4 + m4) * 64) * 16);

            if      (p == 0) stageA(t + 1, 1);
            else if (p == 1) { if (t + 2 < NT) stageB(t + 2, 0); }
            else if (p == 2) { if (t + 2 < NT) stageA(t + 2, 0); }
            else if (p == 3) { if (t + 2 < NT) stageB(t + 2, 1); }
            else if (p == 4) { if (t + 2 < NT) stageA(t + 2, 1); }
            else if (p == 5) { if (t + 3 < NT) stageB(t + 3, 0); }
            else if (p == 6) { if (t + 3 < NT) stageA(t + 3, 0); }
            else             { if (t + 3 < NT) stageB(t + 3, 1); }

            if (p == 3) {
                if (nl) asm volatile("s_waitcnt vmcnt(6)" ::: "memory");
                else    asm volatile("s_waitcnt vmcnt(0)" ::: "memory");
            } else if (p == 7) {
                if (nl) asm volatile("s_waitcnt vmcnt(6)" ::: "memory");
            }

            __builtin_amdgcn_s_setprio(1);
            #pragma unroll
            for (int m4 = 0; m4 < 4; ++m4)
                #pragma unroll
                for (int ni = 0; ni < 4; ++ni)
                    acc[ch * 4 + m4][ni] = __builtin_amdgcn_mfma_f32_16x16x32_bf16(
                        afr[m4], bfr[ni], acc[ch * 4 + m4][ni], 0, 0, 0);
            __builtin_amdgcn_s_setprio(0);
        }
    }

    // ---- epilogue (all paths via LDS for contiguous stores) ----
    const bool doElu = (EPI == 1) || (EPI == 4) || (EPI == 2 && m0 < 1024);
    const long long cb = (long long)bz * cBatch;
    const int crow = (lane >> 4) * 4;

    if constexpr (OUTF32 != 0) {
        float* lt = (float*)smem;
        #pragma unroll
        for (int q = 0; q < 4; ++q) {
            __builtin_amdgcn_s_barrier();
            __builtin_amdgcn_sched_barrier(0);
            if (wr == (q >> 1)) {
                #pragma unroll
                for (int m4 = 0; m4 < 4; ++m4) {
                    const int mi = (q & 1) * 4 + m4;
                    const int lrow = m4 * 16 + crow;
                    const long long r0 = m0 + q * 64 + lrow;
                    #pragma unroll
                    for (int ni = 0; ni < 4; ++ni) {
                        const int lcol = wc * 64 + ni * 16 + la15;
                        float bb = 0.0f;
                        if (!BIASROW && bias) bb = bias[n0 + lcol];
                        #pragma unroll
                        for (int j = 0; j < 4; ++j) {
                            float v = acc[mi][ni][j] + (BIASROW ? bias[r0 + j] : bb);
                            if (doElu) v = (v > 0.0f) ? (v + 1.0f) : __expf(v);
                            lt[(lrow + j) * 260 + lcol] = v;
                        }
                    }
                }
            }
            __builtin_amdgcn_s_barrier();
            #pragma unroll
            for (int it = 0; it < 8; ++it) {
                const int chk = it * 512 + tid;
                const int r   = chk >> 6;
                const int g   = chk & 63;
                float4 v = *(const float4*)(lt + r * 260 + g * 4);
                *(float4*)((float*)Cout + cb + (m0 + q * 64 + r) * ldc + n0 + g * 4) = v;
            }
        }
    } else {
        bf16* lt = (bf16*)smem;
        #pragma unroll
        for (int half = 0; half < 2; ++half) {
            __builtin_amdgcn_s_barrier();
            __builtin_amdgcn_sched_barrier(0);
            if (wr == half) {
                #pragma unroll
                for (int mi = 0; mi < 8; ++mi) {
                    const int lrow = mi * 16 + crow;
                    const long long r0 = m0 + half * 128 + lrow;
                    #pragma unroll
                    for (int ni = 0; ni < 4; ++ni) {
                        const int lcol = wc * 64 + ni * 16 + la15;
                        float bb = 0.0f;
                        if (!BIASROW && bias) bb = bias[n0 + lcol];
                        float ksv = 0.0f;
                        if (EPI == 3 && ksum)
                            ksv = ksum[(long long)batch * D + n0 + lcol];
                        #pragma unroll
                        for (int j = 0; j < 4; ++j) {
                            float v;
                            if (EPI == 3) {
                                v = acc[mi][ni][j] + bias[r0 + j] * ksv;
                            } else {
                                v = acc[mi][ni][j] + (BIASROW ? bias[r0 + j] : bb);
                                if (doElu) v = (v > 0.0f) ? (v + 1.0f) : __expf(v);
                            }
                            lt[(lrow + j) * 264 + lcol] = (bf16)v;
                        }
                    }
                }
            }
            __builtin_amdgcn_s_barrier();
            #pragma unroll
            for (int it = 0; it < 8; ++it) {
                const int chk = it * 512 + tid;
                const int m   = chk >> 5;
                const int nof = (chk & 31) * 8;
                bf16x8 v = *(const bf16x8*)(lt + m * 264 + nof);
                *(bf16x8*)((bf16*)Cout + cb + (m0 + half * 128 + m) * ldc + n0 + nof) = v;
            }
            if constexpr (EPI == 4) {
                // Ksum: per-row (d) partial sums of this half-tile's 256 cols (s)
                const int row = tid >> 2;             // 0..127
                const bf16* rp = lt + row * 264 + (tid & 3) * 64;
                float s = 0.0f;
                #pragma unroll
                for (int e8 = 0; e8 < 8; ++e8) {
                    bf16x8 v = *(const bf16x8*)(rp + e8 * 8);
                    #pragma unroll
                    for (int j = 0; j < 8; ++j) s += (float)v[j];
                }
                s += __shfl_down(s, 2);
                s += __shfl_down(s, 1);
                if ((tid & 3) == 0)
                    atomicAdd(ksum + (long long)batch * D + m0 + half * 128 + row, s);
            }
        }
    }
}

// ---------------- launch ----------------
extern "C" void kernel_launch(void* const* d_in, const int* in_sizes, int n_in,
                              void* d_out, int out_size, void* d_ws, size_t ws_size,
                              hipStream_t stream)
{
    const float* x  = (const float*)d_in[0];
    const float* Wq = (const float*)d_in[1];
    const float* bq = (const float*)d_in[2];
    const float* Wk = (const float*)d_in[3];
    const float* bk = (const float*)d_in[4];
    const float* Wv = (const float*)d_in[5];
    const float* bv = (const float*)d_in[6];
    const float* Wo = (const float*)d_in[7];
    const float* bo = (const float*)d_in[8];
    float* out = (float*)d_out;

    // ws layout (152 MiB):
    //  [0,64M)     xbp [b][s][f]
    //  [64M,96M)   M partials (16 x 2MB slabs) -> MT in even slabs -> then Qb
    //  [96M,96M+32K)  Ksum (fp32 8192)   [+32K,+36K) bvo  (both die before Qb)
    //  [64M,128M)  Qb (written after KVo-gemm; clobbers partials/Ksum/bvo)
    //  [128M,144M) wvT temp (2MB, dead early) -> then KVo (16MB)
    //  [144M,152M) wqb | wob | wkb | Wvo  (2MB each)
    // d_out scratch: Kt [0,64M), xT [64M,128M) — both dead before final write.
    char* ws = (char*)d_ws;
    if (ws_size < (size_t)159383552) return;
    bf16*  xbp  = (bf16*)(ws + 0);
    bf16*  part = (bf16*)(ws + 67108864);
    bf16*  Qb   = (bf16*)(ws + 67108864);
    float* ks   = (float*)(ws + 100663296);
    float* bvo  = (float*)(ws + 100663296 + 32768);
    bf16*  wvT  = (bf16*)(ws + 134217728);
    bf16*  KVo  = (bf16*)(ws + 134217728);
    bf16*  wqb  = (bf16*)(ws + 150994944);
    bf16*  wob  = wqb + 1048576;
    bf16*  wkb  = wob + 1048576;
    bf16*  Wvo  = wkb + 1048576;
    bf16*  Kt   = (bf16*)d_out;            // [b][d][s]
    bf16*  xT   = Kt + NELEM;              // [b][f][s]

    const long long SD = (long long)S * D;
    const long long DD = (long long)D * D;

    // 1) converts + folded-weight prep (x permute + transpose fused, one pass)
    cvt_permute_both<<<dim3(64, 16, 8), 256, 0, stream>>>(x, xbp, xT);
    cvt_w3<<<dim3(1024, 3), 256, 0, stream>>>(Wq, Wo, Wk, wqb, wob, wkb);
    cvt_transpose_1024<<<dim3(16, 16), 256, 0, stream>>>(Wv, wvT);
    bvo_kernel<<<1024, 256, 0, stream>>>(Wo, bv, bvo);
    hipMemsetAsync(ks, 0, B * D * sizeof(float), stream);

    // 2) Wvo[e'][f] = sum_ve Wo[e'][ve] Wv[ve][f]  (A=wob, B=wvT)
    gemm_bt<128, 128, 2, 2, 0, 0, 0><<<dim3(8, 8, 1), 256, 0, stream>>>(
        wob, wvT, nullptr, Wvo, D, D, D, D, 0, 0, 0);

    // 3) K projection + fused Ksum: Kt[b][d][s] = elu(Wk xbp_b^T + bk)+1,
    //    ks[b][d] += row sums (atomic, 16 tiles contribute per row)
    gemm8p<4, 0, 1, 1, 1><<<dim3(16, 4, 8), 512, 0, stream>>>(
        wkb, xbp, bk, ks, Kt, D, D, S, D, 0, SD, SD);

    // 4) M partials: part[2b+h][d][f] = sum_{s half h} Kt[b][d][s] xT[b][f][s]
    gemm8p<0, 0, 0, 2, 0><<<dim3(4, 4, 16), 512, 0, stream>>>(
        Kt, xT, nullptr, nullptr, part, S, S, D, 2048, SD, SD, DD);

    // 5) MT[b] = part[2b] + part[2b+1]  (in-place into even slabs)
    kv_add<<<dim3(512, 8), 256, 0, stream>>>(part);

    // 6) KVo[b][e'][d] = sum_f Wvo[e'][f] MT[b][d][f] + bvo[e']*Ksum[b][d]
    gemm8p<3, 0, 1, 1, 0><<<dim3(4, 4, 8), 512, 0, stream>>>(
        Wvo, part, bvo, ks, KVo, D, D, D, D, 0, 2 * DD, DD);

    // 7) Qb[b][s][d] = elu(xbp_b Wq^T + bq)+1  (clobbers partials/Ksum/bvo)
    gemm8p<1, 0, 0, 1, 0><<<dim3(4, 16, 8), 512, 0, stream>>>(
        xbp, wqb, bq, nullptr, Qb, D, D, D, D, SD, 0, SD);

    // 8) out[s][b][e'] = Qb[b] @ KVo[b]^T + bo  (fp32; C row s at b*D offset)
    gemm8p<0, 1, 0, 1, 0><<<dim3(4, 16, 8), 512, 0, stream>>>(
        Qb, KVo, bo, nullptr, out, D, D, B * D, D,
        SD, DD, (long long)D);
}